// Round 7
// baseline (223.328 us; speedup 1.0000x reference)
//
#include <hip/hip_runtime.h>

#define H     128
#define NP    512
#define NVOX  50000
#define NEDGE 800000
#define EPV   16
#define SLOPE 0.01f
#define GR    16                          // voxel rows per fused k_main block
#define NBLK  (NVOX / GR)                 // 3125 (fallback path)
#define GRG   32                          // rows per k_gemm block
#define NBLKG ((NVOX + GRG - 1) / GRG)    // 1563
#define NEBLK (NVOX / 8)                  // 6250 k_edge blocks (8 voxels each)
#define NPART (NEBLK * 4)                 // 25000 per-wave partials
#define STRH  136
#define VSTR  132
#define C1    2.8853900817779268f         // 2*log2(e)
#define LOG2E 1.4426950408889634f
#define ABLK  3125

#define EXP2(x) __builtin_amdgcn_exp2f(x)
#define LOG2(x) __builtin_amdgcn_logf(x)
#define RCP(x)  __builtin_amdgcn_rcpf(x)

typedef _Float16 h16;
typedef __attribute__((ext_vector_type(4))) _Float16 h16x4;
typedef __attribute__((ext_vector_type(8))) _Float16 h16x8;
typedef __attribute__((ext_vector_type(4))) float    f32x4;

// ==== blocks [0,NP): xp' = (x@Wp+bp)*C1 ; blocks [NP,NP+128): W split ====
__global__ __launch_bounds__(256) void k_pre(const float* __restrict__ x,
                                             const float* __restrict__ Wp,
                                             const float* __restrict__ bp,
                                             const float* __restrict__ Wv,
                                             const float* __restrict__ Wm1,
                                             float* __restrict__ xpout,
                                             h16* __restrict__ WvThi,
                                             h16* __restrict__ WvTlo,
                                             h16* __restrict__ Wm1T) {
    __shared__ float part[H];
    int bid = blockIdx.x;
    int tid = threadIdx.x;
    if (bid < NP) {
        int row = bid;
        int col = tid & 127;
        int kh  = tid >> 7;
        int kbase = kh * 64;
        const float* xr = x + (size_t)row * H;
        float acc = 0.f;
#pragma unroll 8
        for (int k = 0; k < 64; ++k)
            acc = fmaf(xr[kbase + k], Wp[(size_t)(kbase + k) * H + col], acc);
        if (kh == 1) part[col] = acc;
        __syncthreads();
        if (kh == 0) xpout[(size_t)row * H + col] = (acc + part[col] + bp[col]) * C1;
    } else {
        int idx = (bid - NP) * 256 + tid;
        if (idx < 16384) {
            int k = idx >> 7, n = idx & 127;
            float w = Wv[idx];
            h16 hi = (h16)w;
            WvThi[n * H + k] = hi;
            WvTlo[n * H + k] = (h16)(w - (float)hi);
        } else {
            int j = idx - 16384;
            int k = j >> 7, n = j & 127;
            Wm1T[n * H + k] = (h16)Wm1[j];
        }
    }
}

// ======= de-fused GEMM: vv = (v@Wv+bv)*C1 -> global ; mask -> global =======
__global__ __launch_bounds__(256) void k_gemm(
    const float* __restrict__ v,
    const float* __restrict__ bv,  const float* __restrict__ bm1,
    const float* __restrict__ Wm2, const float* __restrict__ bm2,
    const h16* __restrict__ WvThi, const h16* __restrict__ WvTlo,
    const h16* __restrict__ Wm1T,
    float* __restrict__ vvg, float* __restrict__ mask_out)
{
    __shared__ __align__(16) h16 vh[GRG * STRH];
    __shared__ __align__(16) h16 vl[GRG * STRH];
    __shared__ float pmbuf[4][GRG];
    int tid  = threadIdx.x;
    int base = blockIdx.x * GRG;

#pragma unroll
    for (int i = 0; i < 4; ++i) {
        int f  = i * 256 + tid;
        int r  = f >> 5, c4 = f & 31;
        int gr = base + r;
        float4 val = (gr < NVOX) ? *(const float4*)&v[(size_t)gr * H + c4 * 4]
                                 : make_float4(0.f, 0.f, 0.f, 0.f);
        h16x4 hi, lo;
        hi.x = (h16)val.x; lo.x = (h16)(val.x - (float)hi.x);
        hi.y = (h16)val.y; lo.y = (h16)(val.y - (float)hi.y);
        hi.z = (h16)val.z; lo.z = (h16)(val.z - (float)hi.z);
        hi.w = (h16)val.w; lo.w = (h16)(val.w - (float)hi.w);
        *(h16x4*)&vh[r * STRH + c4 * 4] = hi;
        *(h16x4*)&vl[r * STRH + c4 * 4] = lo;
    }
    __syncthreads();

    int wave = tid >> 6, lane = tid & 63;
    int m16 = lane & 15, quad = lane >> 4;
    int cb = wave * 32;

    f32x4 aV[2][2], aM[2][2];
#pragma unroll
    for (int rt = 0; rt < 2; ++rt)
#pragma unroll
        for (int ct = 0; ct < 2; ++ct) { aV[rt][ct] = (f32x4)0.f; aM[rt][ct] = (f32x4)0.f; }

#pragma unroll
    for (int kc = 0; kc < 4; ++kc) {
        int kofs = kc * 32 + quad * 8;
        h16x8 ah[2], al[2];
#pragma unroll
        for (int rt = 0; rt < 2; ++rt) {
            int row = rt * 16 + m16;
            ah[rt] = *(const h16x8*)&vh[row * STRH + kofs];
            al[rt] = *(const h16x8*)&vl[row * STRH + kofs];
        }
#pragma unroll
        for (int ct = 0; ct < 2; ++ct) {
            int n = cb + ct * 16 + m16;
            h16x8 bh = *(const h16x8*)&WvThi[n * H + kofs];
            h16x8 bl = *(const h16x8*)&WvTlo[n * H + kofs];
            h16x8 bm = *(const h16x8*)&Wm1T[n * H + kofs];
#pragma unroll
            for (int rt = 0; rt < 2; ++rt) {
                aV[rt][ct] = __builtin_amdgcn_mfma_f32_16x16x32_f16(ah[rt], bh, aV[rt][ct], 0, 0, 0);
                aV[rt][ct] = __builtin_amdgcn_mfma_f32_16x16x32_f16(al[rt], bh, aV[rt][ct], 0, 0, 0);
                aV[rt][ct] = __builtin_amdgcn_mfma_f32_16x16x32_f16(ah[rt], bl, aV[rt][ct], 0, 0, 0);
                aM[rt][ct] = __builtin_amdgcn_mfma_f32_16x16x32_f16(ah[rt], bm, aM[rt][ct], 0, 0, 0);
            }
        }
    }

    float pml[2][4];
#pragma unroll
    for (int rt = 0; rt < 2; ++rt)
#pragma unroll
        for (int reg = 0; reg < 4; ++reg) pml[rt][reg] = 0.f;
#pragma unroll
    for (int ct = 0; ct < 2; ++ct) {
        int col = cb + ct * 16 + m16;
        float bvc = bv[col], bmc = bm1[col], w2c = Wm2[col];
#pragma unroll
        for (int rt = 0; rt < 2; ++rt)
#pragma unroll
            for (int reg = 0; reg < 4; ++reg) {
                int grow = base + rt * 16 + quad * 4 + reg;
                if (grow < NVOX)
                    vvg[(size_t)grow * H + col] = (aV[rt][ct][reg] + bvc) * C1;
                float m = aM[rt][ct][reg] + bmc;
                m = (m >= 0.f) ? m : SLOPE * m;
                pml[rt][reg] = fmaf(m, w2c, pml[rt][reg]);
            }
    }
#pragma unroll
    for (int off = 8; off >= 1; off >>= 1)
#pragma unroll
        for (int rt = 0; rt < 2; ++rt)
#pragma unroll
            for (int reg = 0; reg < 4; ++reg)
                pml[rt][reg] += __shfl_xor(pml[rt][reg], off, 64);
    if (m16 == 0) {
#pragma unroll
        for (int rt = 0; rt < 2; ++rt)
#pragma unroll
            for (int reg = 0; reg < 4; ++reg)
                pmbuf[wave][rt * 16 + quad * 4 + reg] = pml[rt][reg];
    }
    __syncthreads();
    if (wave == 0 && lane < GRG) {
        int gr = base + lane;
        if (gr < NVOX) {
            float s = pmbuf[0][lane] + pmbuf[1][lane] + pmbuf[2][lane]
                    + pmbuf[3][lane] + bm2[0];
            mask_out[gr] = RCP(1.f + EXP2(-s * LOG2E));
        }
    }
}

// ======= barrier-free edge kernel: 16 lanes/edge, voxel halves paired in-wave ====
// block = 256 thr = 4 waves; wave: 4 groups of 16; vox = blk*8 + w*2 + (gw&1),
// half = gw>>1. Cross-half combine via shfl_xor(32). NO LDS, NO barriers.
__global__ __launch_bounds__(256) void k_edge(
    const float* __restrict__ x,   const float* __restrict__ xp,
    const float* __restrict__ vvg, const int* __restrict__ cei,
    const float* __restrict__ theta, const float* __restrict__ gum,
    float* __restrict__ pout, float* __restrict__ sump,
    float* __restrict__ partial)
{
    int tid  = threadIdx.x;
    int w    = tid >> 6, lane = tid & 63;
    int gw   = lane >> 4, lk = lane & 15;
    int half = gw >> 1;
    int vox  = blockIdx.x * 8 + w * 2 + (gw & 1);

    const float4* th4 = (const float4*)theta;
    float4 t0 = th4[lk], t1 = th4[lk + 16];
    float th2[8];
    th2[0] = -2.f * LOG2E * t0.x; th2[1] = -2.f * LOG2E * t0.y;
    th2[2] = -2.f * LOG2E * t0.z; th2[3] = -2.f * LOG2E * t0.w;
    th2[4] = -2.f * LOG2E * t1.x; th2[5] = -2.f * LOG2E * t1.y;
    th2[6] = -2.f * LOG2E * t1.z; th2[7] = -2.f * LOG2E * t1.w;
    float thsum = LOG2E * (t0.x + t0.y + t0.z + t0.w + t1.x + t1.y + t1.z + t1.w);

    const float4* vv4 = (const float4*)(vvg + (size_t)vox * H);
    float4 B0 = vv4[lk], B1 = vv4[lk + 16];

    float wv8[8];
#pragma unroll
    for (int i = 0; i < 8; ++i)
        wv8[i] = -LOG2E * RCP(LOG2(gum[vox + (half * 8 + i) * NVOX]));

    float4 s0 = make_float4(0.f, 0.f, 0.f, 0.f), s1 = s0;
    float pregs[8];
    float pmax = -1.f, psg = 0.f;
    int   pidx = 0;
#pragma unroll 2
    for (int i = 0; i < 8; ++i) {
        int t   = half * 8 + i;
        int src = cei[vox + t * NVOX];
        const float4* xr = (const float4*)(xp + (size_t)src * H);
        const float4* xo = (const float4*)(x  + (size_t)src * H);
        float4 a0 = xr[lk], a1 = xr[lk + 16];
        float4 c0 = xo[lk], c1 = xo[lk + 16];
        float acc0 = thsum, acc1 = 0.f;
        acc0 = fmaf(th2[0], RCP(EXP2(a0.x + B0.x) + 1.f), acc0);
        acc1 = fmaf(th2[1], RCP(EXP2(a0.y + B0.y) + 1.f), acc1);
        acc0 = fmaf(th2[2], RCP(EXP2(a0.z + B0.z) + 1.f), acc0);
        acc1 = fmaf(th2[3], RCP(EXP2(a0.w + B0.w) + 1.f), acc1);
        acc0 = fmaf(th2[4], RCP(EXP2(a1.x + B1.x) + 1.f), acc0);
        acc1 = fmaf(th2[5], RCP(EXP2(a1.y + B1.y) + 1.f), acc1);
        acc0 = fmaf(th2[6], RCP(EXP2(a1.z + B1.z) + 1.f), acc0);
        acc1 = fmaf(th2[7], RCP(EXP2(a1.w + B1.w) + 1.f), acc1);
        float acc = acc0 + acc1;
        acc += __shfl_xor(acc, 1, 64);   // butterfly over the 16-lane group:
        acc += __shfl_xor(acc, 2, 64);   // all lanes end bitwise-identical
        acc += __shfl_xor(acc, 4, 64);
        acc += __shfl_xor(acc, 8, 64);
        float p = EXP2(acc) * wv8[i];    // exp(theta.tanh + gumbel), TAU=1
        pregs[i] = p;
        if (p > pmax) { pmax = p; pidx = t; }
        psg += p;
        s0.x = fmaf(p, c0.x, s0.x); s0.y = fmaf(p, c0.y, s0.y);
        s0.z = fmaf(p, c0.z, s0.z); s0.w = fmaf(p, c0.w, s0.w);
        s1.x = fmaf(p, c1.x, s1.x); s1.y = fmaf(p, c1.y, s1.y);
        s1.z = fmaf(p, c1.z, s1.z); s1.w = fmaf(p, c1.w, s1.w);
    }
    // combine the two t-halves of this voxel (groups gw and gw^2, lane^32)
    s0.x += __shfl_xor(s0.x, 32, 64); s0.y += __shfl_xor(s0.y, 32, 64);
    s0.z += __shfl_xor(s0.z, 32, 64); s0.w += __shfl_xor(s0.w, 32, 64);
    s1.x += __shfl_xor(s1.x, 32, 64); s1.y += __shfl_xor(s1.y, 32, 64);
    s1.z += __shfl_xor(s1.z, 32, 64); s1.w += __shfl_xor(s1.w, 32, 64);
    float pmo = __shfl_xor(pmax, 32, 64);
    int   pio = __shfl_xor(pidx, 32, 64);
    float pmA = half ? pmo : pmax;  int piA = half ? pio : pidx;
    float pmB = half ? pmax : pmo;  int piB = half ? pidx : pio;
    int am = (pmB > pmA) ? piB : piA;        // first-max (half0 t's are smaller)

    if (half == 0) {
        float4* sp = (float4*)(sump + (size_t)vox * H);
        sp[lk]      = s0;
        sp[lk + 16] = s1;
    }
    if (lk == 0) {
#pragma unroll
        for (int i = 0; i < 8; ++i) {
            int t = half * 8 + i;
            float val = pregs[i];
            pout[vox + t * NVOX] = (t == am) ? -val : val;
        }
    }
    float ps_full = psg + __shfl_xor(psg, 32, 64);
    float contrib = (lk == 0 && half == 0) ? ps_full : 0.f;
    contrib += __shfl_xor(contrib, 16, 64);
    contrib += __shfl_xor(contrib, 32, 64);
    if (lane == 0) partial[blockIdx.x * 4 + w] = contrib;
}

// ---------------- sum partials -> invS ----------------
__global__ __launch_bounds__(256) void k_reduce(const float* __restrict__ partial,
                                                int n, float* __restrict__ invS) {
    __shared__ float wsum[4];
    int tid = threadIdx.x;
    float s = 0.f;
    for (int i = tid; i < n; i += 256) s += partial[i];
#pragma unroll
    for (int off = 32; off >= 1; off >>= 1) s += __shfl_xor(s, off, 64);
    if ((tid & 63) == 0) wsum[tid >> 6] = s;
    __syncthreads();
    if (tid == 0) invS[0] = 1.f / (wsum[0] + wsum[1] + wsum[2] + wsum[3]);
}

// ---- pure streaming finalize ----
__global__ __launch_bounds__(256) void k_out(const float* __restrict__ v,
                                             const float* __restrict__ maskp,
                                             const float* __restrict__ invSp,
                                             float* __restrict__ vout,  // sump in, vout out
                                             float* __restrict__ ybuf,  // +-p in, y out
                                             float* __restrict__ yhard) {
    float invS = invSp[0];
    int tid = threadIdx.x;
    int bid = blockIdx.x;
    if (bid < ABLK) {
#pragma unroll
        for (int r = 0; r < 2; ++r) {
            int i = (bid + r * ABLK) * 256 + tid;
            float4 sp = ((const float4*)vout)[i];
            float4 vv = ((const float4*)v)[i];
            float  m  = maskp[i >> 5] * invS;
            float4 o;
            o.x = fmaf(m, sp.x, vv.x); o.y = fmaf(m, sp.y, vv.y);
            o.z = fmaf(m, sp.z, vv.z); o.w = fmaf(m, sp.w, vv.w);
            ((float4*)vout)[i] = o;
        }
    } else {
        int e = (bid - ABLK) * 256 + tid;
        float pv = ybuf[e];
        ybuf[e]  = fabsf(pv) * invS;
        yhard[e] = (pv < 0.f) ? 1.f : 0.f;
    }
}

// ================= fallback fused k_main (R6 path, small ws) =================
__global__ __launch_bounds__(256) void k_main(
    const float* __restrict__ v,   const float* __restrict__ x,
    const float* __restrict__ bv,  const float* __restrict__ bm1,
    const float* __restrict__ Wm2, const float* __restrict__ bm2,
    const h16* __restrict__ WvThi, const h16* __restrict__ WvTlo,
    const h16* __restrict__ Wm1T,
    const float* __restrict__ xp,  const int* __restrict__ cei,
    const float* __restrict__ theta, const float* __restrict__ gum,
    float* __restrict__ mask_out, float* __restrict__ pout,
    float* __restrict__ sump,     float* __restrict__ partial)
{
    __shared__ __align__(16) char ldsbuf[2 * GR * STRH * 2];
    h16*   vh   = (h16*)ldsbuf;
    h16*   vl   = vh + GR * STRH;
    float* vt   = (float*)ldsbuf;
    float* scmb = (float*)ldsbuf;
    __shared__ float ptile[EPV * GR];
    __shared__ int   ceit[EPV * GR];
    __shared__ float gumt[EPV * GR];
    __shared__ int   amtile[GR];
    __shared__ float pmbuf[4][GR];
    __shared__ float psums[4];

    int tid  = threadIdx.x;
    int base = blockIdx.x * GR;

#pragma unroll
    for (int i = 0; i < 2; ++i) {
        int f  = i * 256 + tid;
        int r  = f >> 5, c4 = f & 31;
        float4 val = *(const float4*)&v[(size_t)(base + r) * H + c4 * 4];
        h16x4 hi, lo;
        hi.x = (h16)val.x; lo.x = (h16)(val.x - (float)hi.x);
        hi.y = (h16)val.y; lo.y = (h16)(val.y - (float)hi.y);
        hi.z = (h16)val.z; lo.z = (h16)(val.z - (float)hi.z);
        hi.w = (h16)val.w; lo.w = (h16)(val.w - (float)hi.w);
        *(h16x4*)&vh[r * STRH + c4 * 4] = hi;
        *(h16x4*)&vl[r * STRH + c4 * 4] = lo;
    }
    {
        int t = tid >> 4, c = tid & 15;
        int e = base + c + t * NVOX;
        ceit[tid] = cei[e];
        gumt[tid] = gum[e];
    }
    __syncthreads();

    int wave = tid >> 6, lane = tid & 63;
    int m16 = lane & 15, quad = lane >> 4;
    int cb = wave * 32;

    f32x4 aV[2], aM[2];
#pragma unroll
    for (int ct = 0; ct < 2; ++ct) { aV[ct] = (f32x4)0.f; aM[ct] = (f32x4)0.f; }

#pragma unroll
    for (int kc = 0; kc < 4; ++kc) {
        int kofs = kc * 32 + quad * 8;
        h16x8 ah = *(const h16x8*)&vh[m16 * STRH + kofs];
        h16x8 al = *(const h16x8*)&vl[m16 * STRH + kofs];
#pragma unroll
        for (int ct = 0; ct < 2; ++ct) {
            int n = cb + ct * 16 + m16;
            h16x8 bh = *(const h16x8*)&WvThi[n * H + kofs];
            h16x8 bl = *(const h16x8*)&WvTlo[n * H + kofs];
            h16x8 bm = *(const h16x8*)&Wm1T[n * H + kofs];
            aV[ct] = __builtin_amdgcn_mfma_f32_16x16x32_f16(ah, bh, aV[ct], 0, 0, 0);
            aV[ct] = __builtin_amdgcn_mfma_f32_16x16x32_f16(al, bh, aV[ct], 0, 0, 0);
            aV[ct] = __builtin_amdgcn_mfma_f32_16x16x32_f16(ah, bl, aV[ct], 0, 0, 0);
            aM[ct] = __builtin_amdgcn_mfma_f32_16x16x32_f16(ah, bm, aM[ct], 0, 0, 0);
        }
    }
    __syncthreads();

    float pml[4] = {0.f, 0.f, 0.f, 0.f};
#pragma unroll
    for (int ct = 0; ct < 2; ++ct) {
        int col = cb + ct * 16 + m16;
        float bvc = bv[col], bmc = bm1[col], w2c = Wm2[col];
#pragma unroll
        for (int reg = 0; reg < 4; ++reg) {
            int row = quad * 4 + reg;
            vt[row * VSTR + col] = (aV[ct][reg] + bvc) * C1;
            float m = aM[ct][reg] + bmc;
            m = (m >= 0.f) ? m : SLOPE * m;
            pml[reg] = fmaf(m, w2c, pml[reg]);
        }
    }
#pragma unroll
    for (int off = 8; off >= 1; off >>= 1)
#pragma unroll
        for (int reg = 0; reg < 4; ++reg)
            pml[reg] += __shfl_xor(pml[reg], off, 64);
    if (m16 == 0) {
#pragma unroll
        for (int reg = 0; reg < 4; ++reg)
            pmbuf[wave][quad * 4 + reg] = pml[reg];
    }
    __syncthreads();
    if (wave == 0 && lane < GR) {
        float s = pmbuf[0][lane] + pmbuf[1][lane] + pmbuf[2][lane]
                + pmbuf[3][lane] + bm2[0];
        mask_out[base + lane] = RCP(1.f + EXP2(-s * LOG2E));
    }

    int g = tid >> 3, lk = tid & 7;
    int vx = g & 15, half = g >> 4;
    float th2[16], thsum = 0.f;
#pragma unroll
    for (int i = 0; i < 4; ++i) {
        float4 t4 = *(const float4*)&theta[(lk + 8 * i) * 4];
        th2[i * 4 + 0] = -2.f * LOG2E * t4.x; th2[i * 4 + 1] = -2.f * LOG2E * t4.y;
        th2[i * 4 + 2] = -2.f * LOG2E * t4.z; th2[i * 4 + 3] = -2.f * LOG2E * t4.w;
        thsum += LOG2E * (t4.x + t4.y + t4.z + t4.w);
    }
    const float* vr = &vt[vx * VSTR];
    float4 b0 = *(const float4*)&vr[(lk +  0) * 4];
    float4 b1 = *(const float4*)&vr[(lk +  8) * 4];
    float4 b2 = *(const float4*)&vr[(lk + 16) * 4];
    float4 b3 = *(const float4*)&vr[(lk + 24) * 4];
    float wv8[8];
#pragma unroll
    for (int i = 0; i < 8; ++i)
        wv8[i] = -LOG2E * RCP(LOG2(gumt[(half * 8 + i) * GR + vx]));
    __syncthreads();

    float4 s0 = make_float4(0.f,0.f,0.f,0.f), s1 = s0, s2 = s0, s3 = s0;
#pragma unroll 2
    for (int i = 0; i < 8; ++i) {
        int t   = half * 8 + i;
        int src = ceit[t * GR + vx];
        const float4* xr = (const float4*)(xp + (size_t)src * H);
        const float4* xo = (const float4*)(x  + (size_t)src * H);
        float4 a0 = xr[lk], a1 = xr[lk + 8], a2 = xr[lk + 16], a3 = xr[lk + 24];
        float4 c0 = xo[lk], c1 = xo[lk + 8], c2 = xo[lk + 16], c3 = xo[lk + 24];
        float acc0 = thsum, acc1 = 0.f;
        acc0 = fmaf(th2[ 0], RCP(EXP2(a0.x + b0.x) + 1.f), acc0);
        acc1 = fmaf(th2[ 1], RCP(EXP2(a0.y + b0.y) + 1.f), acc1);
        acc0 = fmaf(th2[ 2], RCP(EXP2(a0.z + b0.z) + 1.f), acc0);
        acc1 = fmaf(th2[ 3], RCP(EXP2(a0.w + b0.w) + 1.f), acc1);
        acc0 = fmaf(th2[ 4], RCP(EXP2(a1.x + b1.x) + 1.f), acc0);
        acc1 = fmaf(th2[ 5], RCP(EXP2(a1.y + b1.y) + 1.f), acc1);
        acc0 = fmaf(th2[ 6], RCP(EXP2(a1.z + b1.z) + 1.f), acc0);
        acc1 = fmaf(th2[ 7], RCP(EXP2(a1.w + b1.w) + 1.f), acc1);
        acc0 = fmaf(th2[ 8], RCP(EXP2(a2.x + b2.x) + 1.f), acc0);
        acc1 = fmaf(th2[ 9], RCP(EXP2(a2.y + b2.y) + 1.f), acc1);
        acc0 = fmaf(th2[10], RCP(EXP2(a2.z + b2.z) + 1.f), acc0);
        acc1 = fmaf(th2[11], RCP(EXP2(a2.w + b2.w) + 1.f), acc1);
        acc0 = fmaf(th2[12], RCP(EXP2(a3.x + b3.x) + 1.f), acc0);
        acc1 = fmaf(th2[13], RCP(EXP2(a3.y + b3.y) + 1.f), acc1);
        acc0 = fmaf(th2[14], RCP(EXP2(a3.z + b3.z) + 1.f), acc0);
        acc1 = fmaf(th2[15], RCP(EXP2(a3.w + b3.w) + 1.f), acc1);
        float acc = acc0 + acc1;
        acc += __shfl_xor(acc, 4, 64);
        acc += __shfl_xor(acc, 2, 64);
        acc += __shfl_xor(acc, 1, 64);
        float p = EXP2(acc) * wv8[i];
        if (lk == 0) ptile[t * GR + vx] = p;
        s0.x = fmaf(p, c0.x, s0.x); s0.y = fmaf(p, c0.y, s0.y);
        s0.z = fmaf(p, c0.z, s0.z); s0.w = fmaf(p, c0.w, s0.w);
        s1.x = fmaf(p, c1.x, s1.x); s1.y = fmaf(p, c1.y, s1.y);
        s1.z = fmaf(p, c1.z, s1.z); s1.w = fmaf(p, c1.w, s1.w);
        s2.x = fmaf(p, c2.x, s2.x); s2.y = fmaf(p, c2.y, s2.y);
        s2.z = fmaf(p, c2.z, s2.z); s2.w = fmaf(p, c2.w, s2.w);
        s3.x = fmaf(p, c3.x, s3.x); s3.y = fmaf(p, c3.y, s3.y);
        s3.z = fmaf(p, c3.z, s3.z); s3.w = fmaf(p, c3.w, s3.w);
    }
    if (half == 1) {
        float* sc = scmb + vx * 128;
        *(float4*)&sc[(lk +  0) * 4] = s0;
        *(float4*)&sc[(lk +  8) * 4] = s1;
        *(float4*)&sc[(lk + 16) * 4] = s2;
        *(float4*)&sc[(lk + 24) * 4] = s3;
    }
    __syncthreads();
    if (tid < GR) {
        float mx = ptile[tid]; int a = 0;
#pragma unroll
        for (int t = 1; t < EPV; ++t) {
            float yv = ptile[t * GR + tid];
            if (yv > mx) { mx = yv; a = t; }
        }
        amtile[tid] = a;
    }
    if (half == 0) {
        const float* sc = scmb + vx * 128;
        float4 r0 = *(const float4*)&sc[(lk +  0) * 4];
        float4 r1 = *(const float4*)&sc[(lk +  8) * 4];
        float4 r2 = *(const float4*)&sc[(lk + 16) * 4];
        float4 r3 = *(const float4*)&sc[(lk + 24) * 4];
        float* sr = sump + (size_t)(base + vx) * H;
        *(float4*)&sr[(lk +  0) * 4] = make_float4(s0.x+r0.x, s0.y+r0.y, s0.z+r0.z, s0.w+r0.w);
        *(float4*)&sr[(lk +  8) * 4] = make_float4(s1.x+r1.x, s1.y+r1.y, s1.z+r1.z, s1.w+r1.w);
        *(float4*)&sr[(lk + 16) * 4] = make_float4(s2.x+r2.x, s2.y+r2.y, s2.z+r2.z, s2.w+r2.w);
        *(float4*)&sr[(lk + 24) * 4] = make_float4(s3.x+r3.x, s3.y+r3.y, s3.z+r3.z, s3.w+r3.w);
    }
    __syncthreads();
    float pv;
    {
        int t = tid >> 4, c = tid & 15;
        pv = ptile[tid];
        pout[base + c + t * NVOX] = (t == amtile[c]) ? -pv : pv;
    }
    float psum = pv;
#pragma unroll
    for (int off = 32; off >= 1; off >>= 1) psum += __shfl_xor(psum, off, 64);
    if (lane == 0) psums[wave] = psum;
    __syncthreads();
    if (tid == 0)
        partial[blockIdx.x] = psums[0] + psums[1] + psums[2] + psums[3];
}

extern "C" void kernel_launch(void* const* d_in, const int* in_sizes, int n_in,
                              void* d_out, int out_size, void* d_ws, size_t ws_size,
                              hipStream_t stream) {
    (void)in_sizes; (void)n_in; (void)out_size;
    const float* x   = (const float*)d_in[0];
    const float* v   = (const float*)d_in[1];
    const int*   cei = (const int*)d_in[2];
    const float* Wp  = (const float*)d_in[3];
    const float* bp  = (const float*)d_in[4];
    const float* Wv  = (const float*)d_in[5];
    const float* bv  = (const float*)d_in[6];
    const float* Wm1 = (const float*)d_in[7];
    const float* bm1 = (const float*)d_in[8];
    const float* Wm2 = (const float*)d_in[9];
    const float* bm2 = (const float*)d_in[10];
    const float* th  = (const float*)d_in[11];
    const float* gum = (const float*)d_in[12];

    float* out   = (float*)d_out;
    float* vout  = out;                          // [NV*H] sump until k_out
    float* maskp = out + (size_t)NVOX * H;       // [NV]
    float* ybuf  = maskp + NVOX;                 // [E]  +-p until k_out
    float* yhard = ybuf + NEDGE;                 // [E]  scratch until k_out
    float* xp    = yhard;                        // 65536 floats
    h16*   WvThi = (h16*)(yhard + 65536);        // 16384 h16
    h16*   WvTlo = WvThi + 16384;
    h16*   Wm1T  = WvThi + 32768;

    size_t need = ((size_t)NVOX * H + 40000) * sizeof(float);   // vv + partials
    if (ws_size >= need) {
        float* vvg     = (float*)d_ws;                  // 6.4M floats
        float* partial = vvg + (size_t)NVOX * H;        // 25000 floats
        float* invS    = partial + 32768;               // 1 float
        k_pre<<<NP + 128, 256, 0, stream>>>(x, Wp, bp, Wv, Wm1, xp, WvThi, WvTlo, Wm1T);
        k_gemm<<<NBLKG, 256, 0, stream>>>(v, bv, bm1, Wm2, bm2, WvThi, WvTlo, Wm1T,
                                          vvg, maskp);
        k_edge<<<NEBLK, 256, 0, stream>>>(x, xp, vvg, cei, th, gum, ybuf, vout, partial);
        k_reduce<<<1, 256, 0, stream>>>(partial, NPART, invS);
        k_out<<<2 * ABLK, 256, 0, stream>>>(v, maskp, invS, vout, ybuf, yhard);
    } else {
        float* partial = (float*)d_ws;               // NBLK floats
        float* invS    = (float*)d_ws + 4096;        // 1 float
        k_pre<<<NP + 128, 256, 0, stream>>>(x, Wp, bp, Wv, Wm1, xp, WvThi, WvTlo, Wm1T);
        k_main<<<NBLK, 256, 0, stream>>>(v, x, bv, bm1, Wm2, bm2, WvThi, WvTlo, Wm1T,
                                         xp, cei, th, gum, maskp, ybuf, vout, partial);
        k_reduce<<<1, 256, 0, stream>>>(partial, NBLK, invS);
        k_out<<<2 * ABLK, 256, 0, stream>>>(v, maskp, invS, vout, ybuf, yhard);
    }
}

// Round 8
// 180.262 us; speedup vs baseline: 1.2389x; 1.2389x over previous
//
#include <hip/hip_runtime.h>

#define H     128
#define NP    512
#define NVOX  50000
#define NEDGE 800000
#define EPV   16
#define SLOPE 0.01f
#define GR    32                          // voxel rows per k_mainX block
#define NBLK  1563                        // ceil(NVOX/GR)
#define STRH  136                         // padded f16 LDS stride (halves)
#define VSTR  132                         // padded f32 LDS stride (floats)
#define C1    2.8853900817779268f         // 2*log2(e)
#define LOG2E 1.4426950408889634f
#define ABLK  3125                        // k_out part-A blocks

#define EXP2(x) __builtin_amdgcn_exp2f(x)
#define LOG2(x) __builtin_amdgcn_logf(x)
#define RCP(x)  __builtin_amdgcn_rcpf(x)

typedef _Float16 h16;
typedef __attribute__((ext_vector_type(4))) _Float16 h16x4;
typedef __attribute__((ext_vector_type(8))) _Float16 h16x8;
typedef __attribute__((ext_vector_type(4))) float    f32x4;

// ==== blocks [0,NP): xp' = (x@Wp+bp)*C1 ; blocks [NP,NP+128): W split ====
__global__ __launch_bounds__(256) void k_pre(const float* __restrict__ x,
                                             const float* __restrict__ Wp,
                                             const float* __restrict__ bp,
                                             const float* __restrict__ Wv,
                                             const float* __restrict__ Wm1,
                                             float* __restrict__ xpout,
                                             h16* __restrict__ WvThi,
                                             h16* __restrict__ WvTlo,
                                             h16* __restrict__ Wm1T) {
    __shared__ float part[H];
    int bid = blockIdx.x;
    int tid = threadIdx.x;
    if (bid < NP) {
        int row = bid;
        int col = tid & 127;
        int kh  = tid >> 7;
        int kbase = kh * 64;
        const float* xr = x + (size_t)row * H;
        float acc = 0.f;
#pragma unroll 8
        for (int k = 0; k < 64; ++k)
            acc = fmaf(xr[kbase + k], Wp[(size_t)(kbase + k) * H + col], acc);
        if (kh == 1) part[col] = acc;
        __syncthreads();
        if (kh == 0) xpout[(size_t)row * H + col] = (acc + part[col] + bp[col]) * C1;
    } else {
        int idx = (bid - NP) * 256 + tid;
        if (idx < 16384) {
            int k = idx >> 7, n = idx & 127;
            float w = Wv[idx];
            h16 hi = (h16)w;
            WvThi[n * H + k] = hi;
            WvTlo[n * H + k] = (h16)(w - (float)hi);
        } else {
            int j = idx - 16384;
            int k = j >> 7, n = j & 127;
            Wm1T[n * H + k] = (h16)Wm1[j];
        }
    }
}

// ======= fused: vv GEMM (LDS-only), mask, per-edge p (prefetched gathers),
//         sump = sum p*x[src], per-block psum partial =======
__global__ __launch_bounds__(256, 4) void k_mainX(
    const float* __restrict__ v,   const float* __restrict__ x,
    const float* __restrict__ bv,  const float* __restrict__ bm1,
    const float* __restrict__ Wm2, const float* __restrict__ bm2,
    const h16* __restrict__ WvThi, const h16* __restrict__ WvTlo,
    const h16* __restrict__ Wm1T,
    const float* __restrict__ xp,  const int* __restrict__ cei,
    const float* __restrict__ theta, const float* __restrict__ gum,
    float* __restrict__ mask_out, float* __restrict__ pout,
    float* __restrict__ sump,     float* __restrict__ partial)
{
    __shared__ __align__(16) char ldsbuf[2 * GR * STRH * 2];  // 17408 B
    h16*   vh = (h16*)ldsbuf;            // [GR][STRH]
    h16*   vl = vh + GR * STRH;
    float* vt = (float*)ldsbuf;          // [GR][VSTR] f32 vv tile (reuse)
    __shared__ float ptile[EPV * GR];    // [t*GR+c]
    __shared__ int   ceit[EPV * GR];
    __shared__ float gumt[EPV * GR];
    __shared__ int   amtile[GR];
    __shared__ float pmbuf[4][GR];
    __shared__ float psums[4];

    int tid  = threadIdx.x;
    int base = blockIdx.x * GR;

    // ---- stage v tile (f16 hi/lo split) + cei/gum tiles (clamped tail) ----
#pragma unroll
    for (int i = 0; i < 4; ++i) {
        int f  = i * 256 + tid;          // 1024 float4 slots
        int r  = f >> 5, c4 = f & 31;
        int gr = base + r; if (gr >= NVOX) gr = NVOX - 1;
        float4 val = *(const float4*)&v[(size_t)gr * H + c4 * 4];
        h16x4 hi, lo;
        hi.x = (h16)val.x; lo.x = (h16)(val.x - (float)hi.x);
        hi.y = (h16)val.y; lo.y = (h16)(val.y - (float)hi.y);
        hi.z = (h16)val.z; lo.z = (h16)(val.z - (float)hi.z);
        hi.w = (h16)val.w; lo.w = (h16)(val.w - (float)hi.w);
        *(h16x4*)&vh[r * STRH + c4 * 4] = hi;
        *(h16x4*)&vl[r * STRH + c4 * 4] = lo;
    }
#pragma unroll
    for (int it = 0; it < 2; ++it) {
        int idx = it * 256 + tid;        // 512 slots
        int t = idx >> 5, c = idx & 31;
        int vx = base + c; if (vx >= NVOX) vx = NVOX - 1;
        int e = vx + t * NVOX;
        ceit[idx] = cei[e];
        gumt[idx] = gum[e];
    }
    __syncthreads();

    // ---- dual GEMM via MFMA 16x16x32 f16 (split hi/lo for Wv) ----
    int wave = tid >> 6, lane = tid & 63;
    int m16 = lane & 15, quad = lane >> 4;
    int cb = wave * 32;

    f32x4 aV[2][2], aM[2][2];
#pragma unroll
    for (int rt = 0; rt < 2; ++rt)
#pragma unroll
        for (int ct = 0; ct < 2; ++ct) { aV[rt][ct] = (f32x4)0.f; aM[rt][ct] = (f32x4)0.f; }

#pragma unroll
    for (int kc = 0; kc < 4; ++kc) {
        int kofs = kc * 32 + quad * 8;
        h16x8 ah[2], al[2];
#pragma unroll
        for (int rt = 0; rt < 2; ++rt) {
            int row = rt * 16 + m16;
            ah[rt] = *(const h16x8*)&vh[row * STRH + kofs];
            al[rt] = *(const h16x8*)&vl[row * STRH + kofs];
        }
#pragma unroll
        for (int ct = 0; ct < 2; ++ct) {
            int n = cb + ct * 16 + m16;
            h16x8 bh = *(const h16x8*)&WvThi[n * H + kofs];
            h16x8 bl = *(const h16x8*)&WvTlo[n * H + kofs];
            h16x8 bm = *(const h16x8*)&Wm1T[n * H + kofs];
#pragma unroll
            for (int rt = 0; rt < 2; ++rt) {
                aV[rt][ct] = __builtin_amdgcn_mfma_f32_16x16x32_f16(ah[rt], bh, aV[rt][ct], 0, 0, 0);
                aV[rt][ct] = __builtin_amdgcn_mfma_f32_16x16x32_f16(al[rt], bh, aV[rt][ct], 0, 0, 0);
                aV[rt][ct] = __builtin_amdgcn_mfma_f32_16x16x32_f16(ah[rt], bl, aV[rt][ct], 0, 0, 0);
                aM[rt][ct] = __builtin_amdgcn_mfma_f32_16x16x32_f16(ah[rt], bm, aM[rt][ct], 0, 0, 0);
            }
        }
    }
    __syncthreads();                     // vh/vl fully consumed

    // ---- write vv tile (prescaled by C1) to LDS + mask partials ----
    float pml[2][4];
#pragma unroll
    for (int rt = 0; rt < 2; ++rt)
#pragma unroll
        for (int reg = 0; reg < 4; ++reg) pml[rt][reg] = 0.f;
#pragma unroll
    for (int ct = 0; ct < 2; ++ct) {
        int col = cb + ct * 16 + m16;
        float bvc = bv[col], bmc = bm1[col], w2c = Wm2[col];
#pragma unroll
        for (int rt = 0; rt < 2; ++rt)
#pragma unroll
            for (int reg = 0; reg < 4; ++reg) {
                int row = rt * 16 + quad * 4 + reg;
                vt[row * VSTR + col] = (aV[rt][ct][reg] + bvc) * C1;
                float m = aM[rt][ct][reg] + bmc;
                m = (m >= 0.f) ? m : SLOPE * m;
                pml[rt][reg] = fmaf(m, w2c, pml[rt][reg]);
            }
    }
#pragma unroll
    for (int off = 8; off >= 1; off >>= 1)
#pragma unroll
        for (int rt = 0; rt < 2; ++rt)
#pragma unroll
            for (int reg = 0; reg < 4; ++reg)
                pml[rt][reg] += __shfl_xor(pml[rt][reg], off, 64);
    if (m16 == 0) {
#pragma unroll
        for (int rt = 0; rt < 2; ++rt)
#pragma unroll
            for (int reg = 0; reg < 4; ++reg)
                pmbuf[wave][rt * 16 + quad * 4 + reg] = pml[rt][reg];
    }
    __syncthreads();                     // vt + pmbuf visible
    if (wave == 0 && lane < GR) {
        int gr = base + lane;
        if (gr < NVOX) {
            float s = pmbuf[0][lane] + pmbuf[1][lane] + pmbuf[2][lane]
                    + pmbuf[3][lane] + bm2[0];
            mask_out[gr] = RCP(1.f + EXP2(-s * LOG2E));
        }
    }

    // ---- edges: 8 lanes/edge, group g owns voxel base+g, prefetched xp rows ----
    int g = tid >> 3, lk = tid & 7;
    int vox = base + g;
    bool valid = vox < NVOX;
    float th2[16], thsum = 0.f;
#pragma unroll
    for (int i = 0; i < 4; ++i) {
        float4 t4 = *(const float4*)&theta[(lk + 8 * i) * 4];
        th2[i * 4 + 0] = -2.f * LOG2E * t4.x; th2[i * 4 + 1] = -2.f * LOG2E * t4.y;
        th2[i * 4 + 2] = -2.f * LOG2E * t4.z; th2[i * 4 + 3] = -2.f * LOG2E * t4.w;
        thsum += LOG2E * (t4.x + t4.y + t4.z + t4.w);
    }
    const float* vr = &vt[g * VSTR];
    float4 b0 = *(const float4*)&vr[(lk +  0) * 4];
    float4 b1 = *(const float4*)&vr[(lk +  8) * 4];
    float4 b2 = *(const float4*)&vr[(lk + 16) * 4];
    float4 b3 = *(const float4*)&vr[(lk + 24) * 4];

    float4 s0 = make_float4(0.f,0.f,0.f,0.f), s1 = s0, s2 = s0, s3 = s0;
    float psum = 0.f, pmax = -1.f;
    int   pidx = 0;

    int srcC = ceit[g];                  // t = 0
    const float4* xr0 = (const float4*)(xp + (size_t)srcC * H);
    float4 a0 = xr0[lk], a1 = xr0[lk + 8], a2 = xr0[lk + 16], a3 = xr0[lk + 24];

    for (int t = 0; t < EPV; ++t) {
        // prefetch next xp row (the only latency-exposed gather)
        float4 n0, n1, n2, n3;
        int srcN;
        if (t < EPV - 1) {
            srcN = ceit[(t + 1) * GR + g];
            const float4* xrN = (const float4*)(xp + (size_t)srcN * H);
            n0 = xrN[lk]; n1 = xrN[lk + 8]; n2 = xrN[lk + 16]; n3 = xrN[lk + 24];
        } else {
            srcN = srcC; n0 = a0; n1 = a1; n2 = a2; n3 = a3;
        }
        // x row: first use is ~250 cyc away (behind trans+shfl chain)
        const float4* xo = (const float4*)(x + (size_t)srcC * H);
        float4 c0 = xo[lk], c1 = xo[lk + 8], c2 = xo[lk + 16], c3 = xo[lk + 24];
        float wvt = -LOG2E * RCP(LOG2(gumt[t * GR + g]));   // exp(gumbel)

        float acc0 = thsum, acc1 = 0.f;
        acc0 = fmaf(th2[ 0], RCP(EXP2(a0.x + b0.x) + 1.f), acc0);
        acc1 = fmaf(th2[ 1], RCP(EXP2(a0.y + b0.y) + 1.f), acc1);
        acc0 = fmaf(th2[ 2], RCP(EXP2(a0.z + b0.z) + 1.f), acc0);
        acc1 = fmaf(th2[ 3], RCP(EXP2(a0.w + b0.w) + 1.f), acc1);
        acc0 = fmaf(th2[ 4], RCP(EXP2(a1.x + b1.x) + 1.f), acc0);
        acc1 = fmaf(th2[ 5], RCP(EXP2(a1.y + b1.y) + 1.f), acc1);
        acc0 = fmaf(th2[ 6], RCP(EXP2(a1.z + b1.z) + 1.f), acc0);
        acc1 = fmaf(th2[ 7], RCP(EXP2(a1.w + b1.w) + 1.f), acc1);
        acc0 = fmaf(th2[ 8], RCP(EXP2(a2.x + b2.x) + 1.f), acc0);
        acc1 = fmaf(th2[ 9], RCP(EXP2(a2.y + b2.y) + 1.f), acc1);
        acc0 = fmaf(th2[10], RCP(EXP2(a2.z + b2.z) + 1.f), acc0);
        acc1 = fmaf(th2[11], RCP(EXP2(a2.w + b2.w) + 1.f), acc1);
        acc0 = fmaf(th2[12], RCP(EXP2(a3.x + b3.x) + 1.f), acc0);
        acc1 = fmaf(th2[13], RCP(EXP2(a3.y + b3.y) + 1.f), acc1);
        acc0 = fmaf(th2[14], RCP(EXP2(a3.z + b3.z) + 1.f), acc0);
        acc1 = fmaf(th2[15], RCP(EXP2(a3.w + b3.w) + 1.f), acc1);
        float acc = acc0 + acc1;
        acc += __shfl_xor(acc, 4, 64);   // bitwise-identical across the 8 lanes
        acc += __shfl_xor(acc, 2, 64);
        acc += __shfl_xor(acc, 1, 64);
        float p = EXP2(acc) * wvt;       // exp(theta.tanh + gumbel), TAU=1
        if (p > pmax) { pmax = p; pidx = t; }   // strict > = first max
        if (valid) psum += p;
        if (lk == 0) ptile[t * GR + g] = p;
        s0.x = fmaf(p, c0.x, s0.x); s0.y = fmaf(p, c0.y, s0.y);
        s0.z = fmaf(p, c0.z, s0.z); s0.w = fmaf(p, c0.w, s0.w);
        s1.x = fmaf(p, c1.x, s1.x); s1.y = fmaf(p, c1.y, s1.y);
        s1.z = fmaf(p, c1.z, s1.z); s1.w = fmaf(p, c1.w, s1.w);
        s2.x = fmaf(p, c2.x, s2.x); s2.y = fmaf(p, c2.y, s2.y);
        s2.z = fmaf(p, c2.z, s2.z); s2.w = fmaf(p, c2.w, s2.w);
        s3.x = fmaf(p, c3.x, s3.x); s3.y = fmaf(p, c3.y, s3.y);
        s3.z = fmaf(p, c3.z, s3.z); s3.w = fmaf(p, c3.w, s3.w);
        a0 = n0; a1 = n1; a2 = n2; a3 = n3; srcC = srcN;
    }
    if (lk == 0) amtile[g] = pidx;
    if (valid) {
        float* sr = sump + (size_t)vox * H;
        *(float4*)&sr[(lk +  0) * 4] = s0;
        *(float4*)&sr[(lk +  8) * 4] = s1;
        *(float4*)&sr[(lk + 16) * 4] = s2;
        *(float4*)&sr[(lk + 24) * 4] = s3;
    }
    // wave psum: groups occupy disjoint 8-lane slots -> xor 8/16/32 sums each once
    psum += __shfl_xor(psum, 8, 64);
    psum += __shfl_xor(psum, 16, 64);
    psum += __shfl_xor(psum, 32, 64);
    if (lane == 0) psums[wave] = psum;
    __syncthreads();                     // ptile + amtile + psums visible
#pragma unroll
    for (int it = 0; it < 2; ++it) {
        int idx = it * 256 + tid;
        int t = idx >> 5, c = idx & 31;
        int vox2 = base + c;
        if (vox2 < NVOX) {
            float val = ptile[t * GR + c];
            pout[vox2 + t * NVOX] = (t == amtile[c]) ? -val : val;
        }
    }
    if (tid == 0)
        partial[blockIdx.x] = psums[0] + psums[1] + psums[2] + psums[3];
}

// ---- finalize: per-block redundant invS (1563 partials, L2-resident) + stream ----
// blocks [0,ABLK): vout = v + mask*invS*sump ; blocks [ABLK,2*ABLK): y, y_hard
__global__ __launch_bounds__(256) void k_out(const float* __restrict__ v,
                                             const float* __restrict__ maskp,
                                             const float* __restrict__ partial,
                                             float* __restrict__ vout,  // sump in
                                             float* __restrict__ ybuf,  // +-p in
                                             float* __restrict__ yhard) {
    __shared__ float wsum[4];
    int tid = threadIdx.x;
    float s = 0.f;
    for (int i = tid; i < NBLK; i += 256) s += partial[i];
#pragma unroll
    for (int off = 32; off >= 1; off >>= 1) s += __shfl_xor(s, off, 64);
    if ((tid & 63) == 0) wsum[tid >> 6] = s;
    __syncthreads();
    float invS = RCP(wsum[0] + wsum[1] + wsum[2] + wsum[3]);  // identical per block

    int bid = blockIdx.x;
    if (bid < ABLK) {
#pragma unroll
        for (int r = 0; r < 2; ++r) {
            int i = (bid + r * ABLK) * 256 + tid;
            float4 sp = ((const float4*)vout)[i];
            float4 vv = ((const float4*)v)[i];
            float  m  = maskp[i >> 5] * invS;
            float4 o;
            o.x = fmaf(m, sp.x, vv.x); o.y = fmaf(m, sp.y, vv.y);
            o.z = fmaf(m, sp.z, vv.z); o.w = fmaf(m, sp.w, vv.w);
            ((float4*)vout)[i] = o;
        }
    } else {
        int e = (bid - ABLK) * 256 + tid;
        float pv = ybuf[e];
        ybuf[e]  = fabsf(pv) * invS;
        yhard[e] = (pv < 0.f) ? 1.f : 0.f;
    }
}

extern "C" void kernel_launch(void* const* d_in, const int* in_sizes, int n_in,
                              void* d_out, int out_size, void* d_ws, size_t ws_size,
                              hipStream_t stream) {
    (void)in_sizes; (void)n_in; (void)out_size; (void)ws_size;
    const float* x   = (const float*)d_in[0];
    const float* v   = (const float*)d_in[1];
    const int*   cei = (const int*)d_in[2];
    const float* Wp  = (const float*)d_in[3];
    const float* bp  = (const float*)d_in[4];
    const float* Wv  = (const float*)d_in[5];
    const float* bv  = (const float*)d_in[6];
    const float* Wm1 = (const float*)d_in[7];
    const float* bm1 = (const float*)d_in[8];
    const float* Wm2 = (const float*)d_in[9];
    const float* bm2 = (const float*)d_in[10];
    const float* th  = (const float*)d_in[11];
    const float* gum = (const float*)d_in[12];

    float* out   = (float*)d_out;
    float* vout  = out;                          // [NV*H] sump until k_out
    float* maskp = out + (size_t)NVOX * H;       // [NV]
    float* ybuf  = maskp + NVOX;                 // [E]  +-p until k_out
    float* yhard = ybuf + NEDGE;                 // [E]  scratch until k_out
    float* xp    = yhard;                        // 65536 floats
    h16*   WvThi = (h16*)(yhard + 65536);        // 16384 h16
    h16*   WvTlo = WvThi + 16384;
    h16*   Wm1T  = WvThi + 32768;
    float* partial = (float*)d_ws;               // NBLK floats (~6.3 KB)

    k_pre<<<NP + 128, 256, 0, stream>>>(x, Wp, bp, Wv, Wm1, xp, WvThi, WvTlo, Wm1T);
    k_mainX<<<NBLK, 256, 0, stream>>>(v, x, bv, bm1, Wm2, bm2, WvThi, WvTlo, Wm1T,
                                      xp, cei, th, gum, maskp, ybuf, vout, partial);
    k_out<<<2 * ABLK, 256, 0, stream>>>(v, maskp, partial, vout, ybuf, yhard);
}